// Round 8
// baseline (766.500 us; speedup 1.0000x reference)
//
#include <hip/hip_runtime.h>

typedef _Float16 F16;
typedef __attribute__((ext_vector_type(8))) _Float16 f16x8;
typedef __attribute__((ext_vector_type(4))) _Float16 f16x4;
typedef __attribute__((ext_vector_type(4))) float f32x4;

constexpr int NTOK = 8192;   // B*T
constexpr int C    = 1024;   // d_model
constexpr int FF   = 2048;   // d_ff
constexpr int NE   = 8;      // experts
constexpr int NRT  = 72;     // max routed 256-row tiles: 16384/256 + 8
constexpr int NST  = 32;     // shared-expert tiles: 8192/256
constexpr int MAXT = NRT + NST;     // 104
constexpr int SBASE = NRT * 256;    // shared rows start here in H/Y
constexpr int ROWS = SBASE + NTOK;  // 26624

#define MI_CNT 0
#define MI_CUR 8
#define MI_BASE 16
#define MI_TE 32
#define MI_TR (32 + MAXT)

__device__ __forceinline__ void gload16(const void* g, void* l) {
  __builtin_amdgcn_global_load_lds(
      (__attribute__((address_space(1))) void*)g,
      (__attribute__((address_space(3))) void*)l, 16, 0, 0);
}
#define VMCNT2() asm volatile("s_waitcnt vmcnt(2)" ::: "memory")
#define VMCNT0() asm volatile("s_waitcnt vmcnt(0)" ::: "memory")
#define BARR()   __builtin_amdgcn_s_barrier()
#define PRIO1()  __builtin_amdgcn_s_setprio(1)
#define PRIO0()  __builtin_amdgcn_s_setprio(0)

// ------- transpose+cast: src [K][N] fp32 -> dst [N'][K] fp16 ----------------
// MODE 0: N'=N (w_down). MODE 1: gate/up 16-col interleave into WGU:
//   n' = ((n>>4)<<5) | (sel<<4) | (n&15);  z = e*2+sel, e==8 -> shared weights
template <int MODE>
__global__ __launch_bounds__(256) void k_cast_w(const float* __restrict__ w8a,
                                                const float* __restrict__ w1a,
                                                const float* __restrict__ w8b,
                                                const float* __restrict__ w1b,
                                                F16* __restrict__ dst, int K, int N) {
  int z = blockIdx.z;
  const float* src; F16* d; int sel = 0;
  if (MODE == 1) {
    int e = z >> 1; sel = z & 1;
    src = sel ? ((e < NE) ? w8b + (size_t)e * K * N : w1b)
              : ((e < NE) ? w8a + (size_t)e * K * N : w1a);
    d = dst + (size_t)e * 2 * N * K;
  } else {
    src = (z < NE) ? (w8a + (size_t)z * K * N) : w1a;
    d = dst + (size_t)z * N * K;
  }
  __shared__ float t[64][33];
  int n0 = blockIdx.x * 32, k0 = blockIdx.y * 64;
  int tx = threadIdx.x & 31, ty = threadIdx.x >> 5;
#pragma unroll
  for (int i = 0; i < 8; i++)
    t[ty + i * 8][tx] = src[(size_t)(k0 + ty + i * 8) * N + n0 + tx];
  __syncthreads();
  int wx = threadIdx.x & 63, wy = threadIdx.x >> 6;
#pragma unroll
  for (int i = 0; i < 8; i++) {
    int n = n0 + wy + i * 4;
    size_t row = (MODE == 1) ? (size_t)(((n >> 4) << 5) | (sel << 4) | (n & 15))
                             : (size_t)n;
    d[row * K + k0 + wx] = (F16)t[wx][wy + i * 4];
  }
}

// ------- router (+fused x cast): fp64 logits, top-2, softmax ----------------
__global__ __launch_bounds__(256) void k_router(const float* __restrict__ x,
                                                const float* __restrict__ rw,
                                                F16* __restrict__ xh,
                                                int* __restrict__ meta,
                                                int* __restrict__ te0, int* __restrict__ te1,
                                                float* __restrict__ tw0, float* __restrict__ tw1) {
  __shared__ float lrw[NE * C];
  for (int i = threadIdx.x; i < NE * C / 4; i += 256)
    ((float4*)lrw)[i] = ((const float4*)rw)[i];
  __syncthreads();
  int lane = threadIdx.x & 63, wid = threadIdx.x >> 6;
  int t = blockIdx.x * 4 + wid;
  const float* xr = x + (size_t)t * C;
  float xv[16];
#pragma unroll
  for (int i = 0; i < 4; i++) {
    float4 v = ((const float4*)xr)[lane * 4 + i];
    xv[i * 4 + 0] = v.x; xv[i * 4 + 1] = v.y; xv[i * 4 + 2] = v.z; xv[i * 4 + 3] = v.w;
  }
  // fused fp32 -> fp16 cast of x
#pragma unroll
  for (int i = 0; i < 4; i++) {
    f16x4 o;
    o.x = (F16)xv[i * 4 + 0]; o.y = (F16)xv[i * 4 + 1];
    o.z = (F16)xv[i * 4 + 2]; o.w = (F16)xv[i * 4 + 3];
    ((f16x4*)(xh + (size_t)t * C))[lane * 4 + i] = o;
  }
  double lg[NE];
#pragma unroll
  for (int e = 0; e < NE; e++) {
    double s = 0.0;
#pragma unroll
    for (int i = 0; i < 16; i++)
      s += (double)xv[i] * (double)lrw[e * C + lane * 16 + i];
#pragma unroll
    for (int d = 1; d < 64; d <<= 1) s += __shfl_xor(s, d, 64);
    lg[e] = s;
  }
  double b0 = -1e300; int i0 = 0;
#pragma unroll
  for (int e = 0; e < NE; e++) if (lg[e] > b0) { b0 = lg[e]; i0 = e; }
  double b1 = -1e300; int i1 = 0;
#pragma unroll
  for (int e = 0; e < NE; e++) if (e != i0 && lg[e] > b1) { b1 = lg[e]; i1 = e; }
  float ex = __expf((float)(b1 - b0));
  float w0 = 1.f / (1.f + ex), w1 = ex / (1.f + ex);
  if (lane == 0) {
    te0[t] = i0; te1[t] = i1; tw0[t] = w0; tw1[t] = w1;
    atomicAdd(&meta[MI_CNT + i0], 1);
    atomicAdd(&meta[MI_CNT + i1], 1);
  }
}

// ---------------- scan: bases, tile map (routed + shared), pad fill ----------
__global__ __launch_bounds__(256) void k_scan(int* __restrict__ meta,
                                              int* __restrict__ rowtok) {
  __shared__ int s_cnt[NE], s_base[NE];
  if (threadIdx.x == 0) {
    int b = 0, nt = 0;
    for (int e = 0; e < NE; e++) {
      int c = meta[MI_CNT + e];
      s_cnt[e] = c; s_base[e] = b;
      meta[MI_BASE + e] = b;
      meta[MI_CUR + e] = 0;
      int tiles = (c + 255) >> 8;
      for (int t = 0; t < tiles; t++) {
        meta[MI_TE + nt] = e;
        meta[MI_TR + nt] = b + t * 256;
        nt++;
      }
      b += tiles << 8;
    }
    for (int t = nt; t < NRT; t++) meta[MI_TE + t] = -1;
    for (int t = 0; t < NST; t++) {
      meta[MI_TE + NRT + t] = NE;
      meta[MI_TR + NRT + t] = SBASE + t * 256;
    }
  }
  __syncthreads();
  for (int e = 0; e < NE; e++) {
    int c = s_cnt[e], b = s_base[e];
    int al = (c + 255) & ~255;
    for (int i = c + threadIdx.x; i < al; i += 256) rowtok[b + i] = -1;
  }
}

// ---------------- scatter tokens into expert buckets (+slot record) ---------
__global__ __launch_bounds__(256) void k_scatter(const int* __restrict__ te0,
                                                 const int* __restrict__ te1,
                                                 int* __restrict__ meta,
                                                 int* __restrict__ rowtok,
                                                 int* __restrict__ sl0,
                                                 int* __restrict__ sl1) {
  int t = blockIdx.x * 256 + threadIdx.x;
  int e0 = te0[t], e1 = te1[t];
  int p0 = atomicAdd(&meta[MI_CUR + e0], 1);
  int r0 = meta[MI_BASE + e0] + p0;
  rowtok[r0] = t; sl0[t] = r0;
  int p1 = atomicAdd(&meta[MI_CUR + e1], 1);
  int r1 = meta[MI_BASE + e1] + p1;
  rowtok[r1] = t; sl1[t] = r1;
}

// ============ MFMA helper ============
__device__ __forceinline__ void mf16(f32x4 (&acc)[8][4], int base,
                                     const f16x8 (&av)[4], const f16x8 (&bb)[4]) {
#pragma unroll
  for (int f = 0; f < 4; ++f)
#pragma unroll
    for (int ni = 0; ni < 4; ++ni)
      acc[base + f][ni] =
          __builtin_amdgcn_mfma_f32_16x16x32_f16(av[f], bb[ni], acc[base + f][ni], 0, 0, 0);
}

// ======= unified 256x256 grouped GEMM — R6 frame at BK=32 / 64KB LDS ========
// 2 blocks/CU (the occupancy lever). dbuf LDS, 2 barriers/tile, counted
// vmcnt(2) (never drains), unpinned interior, setprio around MFMA clusters.
// Swizzle for 64B rows: chunk ^= (row>>1)&3 (16 rows -> 8 slots, 2-way free).
template <bool G1>
__global__ __launch_bounds__(512, 2) void k_gemm(const F16* __restrict__ Asrc,
                                                 const F16* __restrict__ Wsrc,
                                                 F16* __restrict__ Dst,
                                                 const int* __restrict__ meta,
                                                 const int* __restrict__ rowtok) {
  constexpr int K = G1 ? C : FF;
  constexpr int NT = K / 32;
  const int e = meta[MI_TE + blockIdx.y];
  if (e < 0) return;
  const int row0 = meta[MI_TR + blockIdx.y];
  const int n0 = blockIdx.x * 256;
  const F16* WB = Wsrc + (size_t)e * (size_t)(G1 ? 2 * FF : C) * K;
  __shared__ __align__(16) F16 sA[2][256 * 32];
  __shared__ __align__(16) F16 sB[2][256 * 32];
  const int tid = threadIdx.x, lane = tid & 63, wid = tid >> 6;
  const int wm = wid >> 2, wn = wid & 3;

  // staging: instr i covers rows i*128..i*128+127; 4 threads/row, 16B chunks,
  // source chunk pre-swizzled so LDS stays linear (rule #21)
  const int srow = tid >> 2;                              // 0..127
  const int scol = ((tid & 3) ^ ((srow >> 1) & 3)) << 3;  // pre-swizzled chunk
  const F16 *pa[2], *pb[2];
#pragma unroll
  for (int i = 0; i < 2; ++i) {
    const int r = i * 128 + srow;
    int arow;
    if (G1) {
      int tok = (e == NE) ? (row0 - SBASE + r) : rowtok[row0 + r];
      if (tok < 0) tok = 0;   // pad row: harmless dup, never combined
      arow = tok;
    } else {
      arow = row0 + r;
    }
    pa[i] = Asrc + (size_t)arow * K + scol;
    pb[i] = WB + (size_t)(n0 + i * 128 + srow) * K + scol;
  }
  const int dst0 = wid * 16 * 32;       // wave base within instr-0 region
  const int dst1 = (128 + wid * 16) * 32;

  // fragment LDS offsets (swizzled): row stride 32 elems (64B)
  const int fro = lane & 15, q = lane >> 4;
  int aoff[8], boff[4];
#pragma unroll
  for (int f = 0; f < 8; ++f) {
    const int r = wm * 128 + f * 16 + fro;
    aoff[f] = r * 32 + ((q ^ ((r >> 1) & 3)) << 3);
  }
#pragma unroll
  for (int ni = 0; ni < 4; ++ni) {
    const int c = wn * 64 + ni * 16 + fro;
    boff[ni] = c * 32 + ((q ^ ((c >> 1) & 3)) << 3);
  }

  f32x4 acc[8][4];
  const f32x4 fz = {0.f, 0.f, 0.f, 0.f};
#pragma unroll
  for (int i = 0; i < 8; ++i)
#pragma unroll
    for (int j = 0; j < 4; ++j) acc[i][j] = fz;

  // prologue: stage tile 0 (A then B, 4 loads)
  gload16(pa[0], &sA[0][dst0]);
  gload16(pa[1], &sA[0][dst1]);
  gload16(pb[0], &sB[0][dst0]);
  gload16(pb[1], &sB[0][dst1]);

  for (int t = 0; t < NT; ++t) {
    const F16* sAc = sA[t & 1];
    const F16* sBc = sB[t & 1];
    F16* sAn = sA[(t + 1) & 1];
    F16* sBn = sB[(t + 1) & 1];
    const int gk = (t + 1) * 32;
    const bool st = (t + 1 < NT);

    // stage next-tile A (2 loads); counted wait confirms tile t's A+B while
    // keeping the 2 fresh A-loads in flight across the barrier.
    if (st) {
      gload16(pa[0] + gk, &sAn[dst0]);
      gload16(pa[1] + gk, &sAn[dst1]);
      VMCNT2();
    } else {
      VMCNT0();
    }
    BARR();   // tile t visible to all waves

    f16x8 bb[4], av[4];
#pragma unroll
    for (int ni = 0; ni < 4; ++ni) bb[ni] = *(const f16x8*)&sBc[boff[ni]];
#pragma unroll
    for (int f = 0; f < 4; ++f) av[f] = *(const f16x8*)&sAc[aoff[f]];
    PRIO1(); mf16(acc, 0, av, bb); PRIO0();

    if (st) {
      gload16(pb[0] + gk, &sBn[dst0]);
      gload16(pb[1] + gk, &sBn[dst1]);
    }
#pragma unroll
    for (int f = 0; f < 4; ++f) av[f] = *(const f16x8*)&sAc[aoff[4 + f]];
    PRIO1(); mf16(acc, 4, av, bb); PRIO0();

    if (st) BARR();   // read-complete: next iter's staging overwrites buf cur
  }

  const int erow = (lane >> 4) << 2, ecol = lane & 15;
  if (G1) {
    // pair (ni even=gate, ni odd=up) -> silu fuse -> H f16
    const int hb = (n0 >> 1) + wn * 32;
#pragma unroll
    for (int mi = 0; mi < 8; ++mi)
#pragma unroll
      for (int pp = 0; pp < 2; ++pp)
#pragma unroll
        for (int j = 0; j < 4; ++j) {
          const int grow = row0 + wm * 128 + mi * 16 + erow + j;
          const float gv = acc[mi][2 * pp][j], uv = acc[mi][2 * pp + 1][j];
          const float h = gv / (1.f + __expf(-gv)) * uv;
          Dst[(size_t)grow * FF + hb + pp * 16 + ecol] = (F16)h;
        }
  } else {
#pragma unroll
    for (int mi = 0; mi < 8; ++mi)
#pragma unroll
      for (int ni = 0; ni < 4; ++ni)
#pragma unroll
        for (int j = 0; j < 4; ++j) {
          const int grow = row0 + wm * 128 + mi * 16 + erow + j;
          Dst[(size_t)grow * C + n0 + wn * 64 + ni * 16 + ecol] = (F16)acc[mi][ni][j];
        }
  }
}

// ---------------- combine: out = w0*Y[r0] + w1*Y[r1] + Y[shared] ------------
__global__ __launch_bounds__(256) void k_combine(const F16* __restrict__ Y,
                                                 const int* __restrict__ sl0,
                                                 const int* __restrict__ sl1,
                                                 const float* __restrict__ tw0,
                                                 const float* __restrict__ tw1,
                                                 float* __restrict__ out) {
  int idx = blockIdx.x * 256 + threadIdx.x;
  int t = idx >> 7, cg = idx & 127;
  int r0 = sl0[t], r1 = sl1[t];
  float w0 = tw0[t], w1 = tw1[t];
  f16x8 y0 = *(const f16x8*)&Y[(size_t)r0 * C + cg * 8];
  f16x8 y1 = *(const f16x8*)&Y[(size_t)r1 * C + cg * 8];
  f16x8 ys = *(const f16x8*)&Y[(size_t)(SBASE + t) * C + cg * 8];
  float o[8];
#pragma unroll
  for (int j = 0; j < 8; j++)
    o[j] = w0 * (float)y0[j] + w1 * (float)y1[j] + (float)ys[j];
  float* op = out + (size_t)t * C + cg * 8;
  ((float4*)op)[0] = make_float4(o[0], o[1], o[2], o[3]);
  ((float4*)op)[1] = make_float4(o[4], o[5], o[6], o[7]);
}

// ---------------- host launch ----------------
extern "C" void kernel_launch(void* const* d_in, const int* in_sizes, int n_in,
                              void* d_out, int out_size, void* d_ws, size_t ws_size,
                              hipStream_t stream) {
  const float* x  = (const float*)d_in[0];
  const float* rw = (const float*)d_in[1];
  const float* wgate = (const float*)d_in[2];
  const float* wup   = (const float*)d_in[3];
  const float* wdown = (const float*)d_in[4];
  const float* sg = (const float*)d_in[5];
  const float* su = (const float*)d_in[6];
  const float* sd = (const float*)d_in[7];
  float* out = (float*)d_out;

  char* ws = (char*)d_ws;
  size_t o = 0;
  auto alloc = [&](size_t bytes) -> void* {
    void* p = ws + o;
    o += (bytes + 255) & ~(size_t)255;
    return p;
  };
  F16* xh  = (F16*)alloc((size_t)NTOK * C * 2);
  F16* WGU = (F16*)alloc((size_t)9 * 2 * FF * C * 2);
  F16* WD  = (F16*)alloc((size_t)9 * C * FF * 2);
  F16* Hb  = (F16*)alloc((size_t)ROWS * FF * 2);
  int* rowtok = (int*)alloc((size_t)SBASE * 4);
  int* meta = (int*)alloc(2048);
  int* te0 = (int*)alloc((size_t)NTOK * 4);
  int* te1 = (int*)alloc((size_t)NTOK * 4);
  float* tw0 = (float*)alloc((size_t)NTOK * 4);
  float* tw1 = (float*)alloc((size_t)NTOK * 4);
  int* sl0 = (int*)alloc((size_t)NTOK * 4);
  int* sl1 = (int*)alloc((size_t)NTOK * 4);
  if (o > ws_size) return;
  F16* Yb = WGU;   // overlay: WGU dead after gemm1; Y (54.5MB) < WGU (75.5MB)

  hipMemsetAsync(meta, 0, 1024, stream);
  k_cast_w<1><<<dim3(FF / 32, C / 64, 18), 256, 0, stream>>>(wgate, sg, wup, su, WGU, C, FF);
  k_cast_w<0><<<dim3(C / 32, FF / 64, 9), 256, 0, stream>>>(wdown, sd, nullptr, nullptr, WD, FF, C);
  k_router<<<NTOK / 4, 256, 0, stream>>>(x, rw, xh, meta, te0, te1, tw0, tw1);
  k_scan<<<1, 256, 0, stream>>>(meta, rowtok);
  k_scatter<<<NTOK / 256, 256, 0, stream>>>(te0, te1, meta, rowtok, sl0, sl1);
  k_gemm<true><<<dim3(2 * FF / 256, MAXT), 512, 0, stream>>>(xh, WGU, Hb, meta, rowtok);
  k_gemm<false><<<dim3(C / 256, MAXT), 512, 0, stream>>>(Hb, WD, Yb, meta, rowtok);
  k_combine<<<NTOK * (C / 8) / 256, 256, 0, stream>>>(Yb, sl0, sl1, tw0, tw1, out);
}

// Round 9
// 711.044 us; speedup vs baseline: 1.0780x; 1.0780x over previous
//
#include <hip/hip_runtime.h>

typedef _Float16 F16;
typedef __attribute__((ext_vector_type(8))) _Float16 f16x8;
typedef __attribute__((ext_vector_type(4))) _Float16 f16x4;
typedef __attribute__((ext_vector_type(4))) float f32x4;

constexpr int NTOK = 8192;   // B*T
constexpr int C    = 1024;   // d_model
constexpr int FF   = 2048;   // d_ff
constexpr int NE   = 8;      // experts
constexpr int NRT  = 72;     // max routed 256-row tiles: 16384/256 + 8
constexpr int NST  = 32;     // shared-expert tiles: 8192/256
constexpr int MAXT = NRT + NST;     // 104
constexpr int SBASE = NRT * 256;    // shared rows start here in H/Y
constexpr int ROWS = SBASE + NTOK;  // 26624

constexpr int NBWGU = 18 * 512;     // gate/up cast blocks (64x64 tiles)
constexpr int NBWD  = 9 * 512;      // w_down cast blocks
constexpr int NBRT  = NTOK / 4;     // router blocks

#define MI_CNT 0
#define MI_CUR 8
#define MI_BASE 16
#define MI_TE 32
#define MI_TR (32 + MAXT)

__device__ __forceinline__ void gload16(const void* g, void* l) {
  __builtin_amdgcn_global_load_lds(
      (__attribute__((address_space(1))) void*)g,
      (__attribute__((address_space(3))) void*)l, 16, 0, 0);
}
#define VMCNT4() asm volatile("s_waitcnt vmcnt(4)" ::: "memory")
#define VMCNT0() asm volatile("s_waitcnt vmcnt(0)" ::: "memory")
#define BARR()   __builtin_amdgcn_s_barrier()
#define PRIO1()  __builtin_amdgcn_s_setprio(1)
#define PRIO0()  __builtin_amdgcn_s_setprio(0)

// ======= merged prep: weight transpose+cast (vectorized) + router ===========
// blocks [0, NBWGU): gate/up -> WGU [N'][K] fp16, 16-col interleave
//   n' = ((n>>4)<<5) | (sel<<4) | (n&15)
// blocks [NBWGU, NBWGU+NBWD): w_down/sd -> WD [N][K] fp16
// blocks [.., +NBRT): router fp64 logits + top-2 softmax + fused x fp16 cast
__global__ __launch_bounds__(256) void k_prep(
    const float* __restrict__ x, const float* __restrict__ rw,
    const float* __restrict__ wgate, const float* __restrict__ sg,
    const float* __restrict__ wup, const float* __restrict__ su,
    const float* __restrict__ wdown, const float* __restrict__ sd,
    F16* __restrict__ WGU, F16* __restrict__ WD, F16* __restrict__ xh,
    int* __restrict__ meta, int* __restrict__ te0, int* __restrict__ te1,
    float* __restrict__ tw0, float* __restrict__ tw1) {
  __shared__ __align__(16) char smraw[NE * C * 4];   // 32 KB
  const int id = blockIdx.x, tid = threadIdx.x;

  if (id < NBWGU + NBWD) {
    // ---------------- transpose+cast a 64x64 tile ----------------
    float(*t)[65] = (float(*)[65])smraw;
    int nt, kt, K, N, sel = 0;
    bool il;
    const float* src;
    F16* dst;
    if (id < NBWGU) {
      const int z = id >> 9, rem = id & 511;
      nt = rem & 31; kt = rem >> 5;            // N=2048: 32 n-tiles, 16 k-tiles
      K = C; N = FF; il = true; sel = z & 1;
      const int e = z >> 1;
      src = sel ? ((e < NE) ? wup + (size_t)e * C * FF : su)
                : ((e < NE) ? wgate + (size_t)e * C * FF : sg);
      dst = WGU + (size_t)e * 2 * FF * C;
    } else {
      const int id2 = id - NBWGU;
      const int z = id2 >> 9, rem = id2 & 511;
      nt = rem & 15; kt = rem >> 4;            // N=1024: 16 n-tiles, 32 k-tiles
      K = FF; N = C; il = false;
      src = (z < NE) ? wdown + (size_t)z * FF * C : sd;
      dst = WD + (size_t)z * C * FF;
    }
    const int n0 = nt * 64, k0 = kt * 64;
    const int rc = tid >> 4, cc = (tid & 15) * 4;
#pragma unroll
    for (int i = 0; i < 4; i++) {
      const int r = rc + i * 16;   // k-local
      const float4 v = *(const float4*)&src[(size_t)(k0 + r) * N + n0 + cc];
      t[r][cc + 0] = v.x; t[r][cc + 1] = v.y; t[r][cc + 2] = v.z; t[r][cc + 3] = v.w;
    }
    __syncthreads();
    const int oct = tid & 7;
#pragma unroll
    for (int j = 0; j < 2; j++) {
      const int nl = (tid >> 3) + j * 32;
      f16x8 o;
#pragma unroll
      for (int u = 0; u < 8; u++) o[u] = (F16)t[oct * 8 + u][nl];
      const int n = n0 + nl;
      const size_t row = il ? (size_t)(((n >> 4) << 5) | (sel << 4) | (n & 15))
                            : (size_t)n;
      *(f16x8*)&dst[row * K + k0 + oct * 8] = o;
    }
    return;
  }

  // ---------------- router (+fused x cast) ----------------
  float* lrw = (float*)smraw;
  for (int i = tid; i < NE * C / 4; i += 256)
    ((float4*)lrw)[i] = ((const float4*)rw)[i];
  __syncthreads();
  const int rb = id - NBWGU - NBWD;
  const int lane = tid & 63, wid = tid >> 6;
  const int tok = rb * 4 + wid;
  const float* xr = x + (size_t)tok * C;
  float xv[16];
#pragma unroll
  for (int i = 0; i < 4; i++) {
    float4 v = ((const float4*)xr)[lane * 4 + i];
    xv[i * 4 + 0] = v.x; xv[i * 4 + 1] = v.y; xv[i * 4 + 2] = v.z; xv[i * 4 + 3] = v.w;
  }
#pragma unroll
  for (int i = 0; i < 4; i++) {
    f16x4 o;
    o.x = (F16)xv[i * 4 + 0]; o.y = (F16)xv[i * 4 + 1];
    o.z = (F16)xv[i * 4 + 2]; o.w = (F16)xv[i * 4 + 3];
    ((f16x4*)(xh + (size_t)tok * C))[lane * 4 + i] = o;
  }
  double lg[NE];
#pragma unroll
  for (int e = 0; e < NE; e++) {
    double s = 0.0;
#pragma unroll
    for (int i = 0; i < 16; i++)
      s += (double)xv[i] * (double)lrw[e * C + lane * 16 + i];
#pragma unroll
    for (int d = 1; d < 64; d <<= 1) s += __shfl_xor(s, d, 64);
    lg[e] = s;
  }
  double b0 = -1e300; int i0 = 0;
#pragma unroll
  for (int e = 0; e < NE; e++) if (lg[e] > b0) { b0 = lg[e]; i0 = e; }
  double b1 = -1e300; int i1 = 0;
#pragma unroll
  for (int e = 0; e < NE; e++) if (e != i0 && lg[e] > b1) { b1 = lg[e]; i1 = e; }
  const float ex = __expf((float)(b1 - b0));
  const float w0 = 1.f / (1.f + ex), w1 = ex / (1.f + ex);
  if (lane == 0) {
    te0[tok] = i0; te1[tok] = i1; tw0[tok] = w0; tw1[tok] = w1;
    atomicAdd(&meta[MI_CNT + i0], 1);
    atomicAdd(&meta[MI_CNT + i1], 1);
  }
}

// ---------------- scan: bases, tile map (routed + shared), pad fill ----------
__global__ __launch_bounds__(256) void k_scan(int* __restrict__ meta,
                                              int* __restrict__ rowtok) {
  __shared__ int s_cnt[NE], s_base[NE];
  if (threadIdx.x == 0) {
    int b = 0, nt = 0;
    for (int e = 0; e < NE; e++) {
      int c = meta[MI_CNT + e];
      s_cnt[e] = c; s_base[e] = b;
      meta[MI_BASE + e] = b;
      meta[MI_CUR + e] = 0;
      int tiles = (c + 255) >> 8;
      for (int t = 0; t < tiles; t++) {
        meta[MI_TE + nt] = e;
        meta[MI_TR + nt] = b + t * 256;
        nt++;
      }
      b += tiles << 8;
    }
    for (int t = nt; t < NRT; t++) meta[MI_TE + t] = -1;
    for (int t = 0; t < NST; t++) {
      meta[MI_TE + NRT + t] = NE;
      meta[MI_TR + NRT + t] = SBASE + t * 256;
    }
  }
  __syncthreads();
  for (int e = 0; e < NE; e++) {
    int c = s_cnt[e], b = s_base[e];
    int al = (c + 255) & ~255;
    for (int i = c + threadIdx.x; i < al; i += 256) rowtok[b + i] = -1;
  }
}

// ---------------- scatter tokens into expert buckets (+slot record) ---------
__global__ __launch_bounds__(256) void k_scatter(const int* __restrict__ te0,
                                                 const int* __restrict__ te1,
                                                 int* __restrict__ meta,
                                                 int* __restrict__ rowtok,
                                                 int* __restrict__ sl0,
                                                 int* __restrict__ sl1) {
  int t = blockIdx.x * 256 + threadIdx.x;
  int e0 = te0[t], e1 = te1[t];
  int p0 = atomicAdd(&meta[MI_CUR + e0], 1);
  int r0 = meta[MI_BASE + e0] + p0;
  rowtok[r0] = t; sl0[t] = r0;
  int p1 = atomicAdd(&meta[MI_CUR + e1], 1);
  int r1 = meta[MI_BASE + e1] + p1;
  rowtok[r1] = t; sl1[t] = r1;
}

// ============ MFMA / ds_read helpers (pure code, no fences) ============
__device__ __forceinline__ void read_a(f16x8 (&ar)[2][2], const F16* sAc,
                                       const int* aoff, int m0) {
  ar[0][0] = *(const f16x8*)&sAc[aoff[m0]];
  ar[0][1] = *(const f16x8*)&sAc[aoff[m0] ^ 32];
  ar[1][0] = *(const f16x8*)&sAc[aoff[m0 + 1]];
  ar[1][1] = *(const f16x8*)&sAc[aoff[m0 + 1] ^ 32];
}
__device__ __forceinline__ void mfma_pair(f32x4 (&a0)[4], f32x4 (&a1)[4],
                                          const f16x8 (&ar)[2][2],
                                          const f16x8 (&bb)[4][2]) {
#pragma unroll
  for (int ni = 0; ni < 4; ++ni) {
    a0[ni] = __builtin_amdgcn_mfma_f32_16x16x32_f16(ar[0][0], bb[ni][0], a0[ni], 0, 0, 0);
    a1[ni] = __builtin_amdgcn_mfma_f32_16x16x32_f16(ar[1][0], bb[ni][0], a1[ni], 0, 0, 0);
  }
#pragma unroll
  for (int ni = 0; ni < 4; ++ni) {
    a0[ni] = __builtin_amdgcn_mfma_f32_16x16x32_f16(ar[0][1], bb[ni][1], a0[ni], 0, 0, 0);
    a1[ni] = __builtin_amdgcn_mfma_f32_16x16x32_f16(ar[1][1], bb[ni][1], a1[ni], 0, 0, 0);
  }
}

// ======= unified 256x256 grouped GEMM — R6 frame, B-panel-major grid ========
// blockIdx.x = y-tile (fast): consecutive blocks share the expert B-panel
// (L2-resident within an expert run). blockIdx.y = n-block.
// BK=64, dbuf LDS, 2 barriers/tile, counted vmcnt(4) (never drains),
// unpinned interior, setprio around MFMA clusters.
template <bool G1>
__global__ __launch_bounds__(512, 2) void k_gemm(const F16* __restrict__ Asrc,
                                                 const F16* __restrict__ Wsrc,
                                                 F16* __restrict__ Dst,
                                                 const int* __restrict__ meta,
                                                 const int* __restrict__ rowtok) {
  constexpr int K = G1 ? C : FF;
  constexpr int NT = K / 64;
  const int e = meta[MI_TE + blockIdx.x];
  if (e < 0) return;
  const int row0 = meta[MI_TR + blockIdx.x];
  const int n0 = blockIdx.y * 256;
  const F16* WB = Wsrc + (size_t)e * (size_t)(G1 ? 2 * FF : C) * K;
  __shared__ __align__(16) F16 sA[2][256 * 64];
  __shared__ __align__(16) F16 sB[2][256 * 64];
  const int tid = threadIdx.x, lane = tid & 63, wid = tid >> 6;
  const int wm = wid >> 2, wn = wid & 3;

  // staging: instr i covers rows i*64..i*64+63; 8 threads/row, 16B chunks,
  // source chunk pre-swizzled so LDS stays linear (rule #21)
  const int srow = tid >> 3;
  const int scol = ((tid & 7) ^ (srow & 7)) << 3;
  const F16 *pa[4], *pb[4];
#pragma unroll
  for (int i = 0; i < 4; ++i) {
    const int r = i * 64 + srow;
    int arow;
    if (G1) {
      int tok = (e == NE) ? (row0 - SBASE + r) : rowtok[row0 + r];
      if (tok < 0) tok = 0;   // pad row: harmless dup, never combined
      arow = tok;
    } else {
      arow = row0 + r;
    }
    pa[i] = Asrc + (size_t)arow * K + scol;
    pb[i] = WB + (size_t)(n0 + i * 64 + srow) * K + scol;
  }
  const int ldsrow = wid * 8;

  // fragment LDS offsets (swizzled); k-slice 1 = ^32
  const int fro = lane & 15, q = lane >> 4;
  int aoff[8], boff[4];
#pragma unroll
  for (int f = 0; f < 8; ++f) {
    const int r = wm * 128 + f * 16 + fro;
    aoff[f] = r * 64 + ((q ^ (r & 7)) << 3);
  }
#pragma unroll
  for (int ni = 0; ni < 4; ++ni) {
    const int r = wn * 64 + ni * 16 + fro;
    boff[ni] = r * 64 + ((q ^ (r & 7)) << 3);
  }

  f32x4 acc[8][4];
  const f32x4 fz = {0.f, 0.f, 0.f, 0.f};
#pragma unroll
  for (int i = 0; i < 8; ++i)
#pragma unroll
    for (int j = 0; j < 4; ++j) acc[i][j] = fz;

  // prologue: stage tile 0 (8 loads)
#pragma unroll
  for (int i = 0; i < 4; ++i) {
    gload16(pa[i], &sA[0][(i * 64 + ldsrow) * 64]);
    gload16(pb[i], &sB[0][(i * 64 + ldsrow) * 64]);
  }

  for (int t = 0; t < NT; ++t) {
    const F16* sAc = sA[t & 1];
    const F16* sBc = sB[t & 1];
    F16* sAn = sA[(t + 1) & 1];
    F16* sBn = sB[(t + 1) & 1];
    const int gk = (t + 1) * 64;
    const bool st = (t + 1 < NT);

    // stage next-tile A (4 loads), then counted wait: tile t's loads are >=4
    // phases old -> no drain; the 4 A-loads stay in flight across the barrier.
    if (st) {
#pragma unroll
      for (int i = 0; i < 4; ++i)
        gload16(pa[i] + gk, &sAn[(i * 64 + ldsrow) * 64]);
      VMCNT4();
    } else {
      VMCNT0();
    }
    BARR();   // tile t visible to all waves

    f16x8 bb[4][2], ar[2][2];
#pragma unroll
    for (int ni = 0; ni < 4; ++ni) {
      bb[ni][0] = *(const f16x8*)&sBc[boff[ni]];
      bb[ni][1] = *(const f16x8*)&sBc[boff[ni] ^ 32];
    }

    read_a(ar, sAc, aoff, 0);
    PRIO1(); mfma_pair(acc[0], acc[1], ar, bb); PRIO0();
    if (st) {
      gload16(pb[0] + gk, &sBn[ldsrow * 64]);
      gload16(pb[1] + gk, &sBn[(64 + ldsrow) * 64]);
    }
    read_a(ar, sAc, aoff, 2);
    PRIO1(); mfma_pair(acc[2], acc[3], ar, bb); PRIO0();
    if (st) {
      gload16(pb[2] + gk, &sBn[(128 + ldsrow) * 64]);
      gload16(pb[3] + gk, &sBn[(192 + ldsrow) * 64]);
    }
    read_a(ar, sAc, aoff, 4);
    PRIO1(); mfma_pair(acc[4], acc[5], ar, bb); PRIO0();
    read_a(ar, sAc, aoff, 6);
    PRIO1(); mfma_pair(acc[6], acc[7], ar, bb); PRIO0();

    if (st) BARR();   // read-complete: next iter's staging overwrites buf cur
  }

  const int erow = (lane >> 4) << 2, ecol = lane & 15;
  if (G1) {
    // pair (ni even=gate, ni odd=up) -> silu fuse -> H f16
    const int hb = (n0 >> 1) + wn * 32;
#pragma unroll
    for (int mi = 0; mi < 8; ++mi)
#pragma unroll
      for (int pp = 0; pp < 2; ++pp)
#pragma unroll
        for (int j = 0; j < 4; ++j) {
          const int grow = row0 + wm * 128 + mi * 16 + erow + j;
          const float gv = acc[mi][2 * pp][j], uv = acc[mi][2 * pp + 1][j];
          const float h = gv / (1.f + __expf(-gv)) * uv;
          Dst[(size_t)grow * FF + hb + pp * 16 + ecol] = (F16)h;
        }
  } else {
#pragma unroll
    for (int mi = 0; mi < 8; ++mi)
#pragma unroll
      for (int ni = 0; ni < 4; ++ni)
#pragma unroll
        for (int j = 0; j < 4; ++j) {
          const int grow = row0 + wm * 128 + mi * 16 + erow + j;
          Dst[(size_t)grow * C + n0 + wn * 64 + ni * 16 + ecol] = (F16)acc[mi][ni][j];
        }
  }
}

// ---------------- combine: out = w0*Y[r0] + w1*Y[r1] + Y[shared] ------------
__global__ __launch_bounds__(256) void k_combine(const F16* __restrict__ Y,
                                                 const int* __restrict__ sl0,
                                                 const int* __restrict__ sl1,
                                                 const float* __restrict__ tw0,
                                                 const float* __restrict__ tw1,
                                                 float* __restrict__ out) {
  int idx = blockIdx.x * 256 + threadIdx.x;
  int t = idx >> 7, cg = idx & 127;
  int r0 = sl0[t], r1 = sl1[t];
  float w0 = tw0[t], w1 = tw1[t];
  f16x8 y0 = *(const f16x8*)&Y[(size_t)r0 * C + cg * 8];
  f16x8 y1 = *(const f16x8*)&Y[(size_t)r1 * C + cg * 8];
  f16x8 ys = *(const f16x8*)&Y[(size_t)(SBASE + t) * C + cg * 8];
  float o[8];
#pragma unroll
  for (int j = 0; j < 8; j++)
    o[j] = w0 * (float)y0[j] + w1 * (float)y1[j] + (float)ys[j];
  float* op = out + (size_t)t * C + cg * 8;
  ((float4*)op)[0] = make_float4(o[0], o[1], o[2], o[3]);
  ((float4*)op)[1] = make_float4(o[4], o[5], o[6], o[7]);
}

// ---------------- host launch ----------------
extern "C" void kernel_launch(void* const* d_in, const int* in_sizes, int n_in,
                              void* d_out, int out_size, void* d_ws, size_t ws_size,
                              hipStream_t stream) {
  const float* x  = (const float*)d_in[0];
  const float* rw = (const float*)d_in[1];
  const float* wgate = (const float*)d_in[2];
  const float* wup   = (const float*)d_in[3];
  const float* wdown = (const float*)d_in[4];
  const float* sg = (const float*)d_in[5];
  const float* su = (const float*)d_in[6];
  const float* sd = (const float*)d_in[7];
  float* out = (float*)d_out;

  char* ws = (char*)d_ws;
  size_t o = 0;
  auto alloc = [&](size_t bytes) -> void* {
    void* p = ws + o;
    o += (bytes + 255) & ~(size_t)255;
    return p;
  };
  F16* xh  = (F16*)alloc((size_t)NTOK * C * 2);
  F16* WGU = (F16*)alloc((size_t)9 * 2 * FF * C * 2);
  F16* WD  = (F16*)alloc((size_t)9 * C * FF * 2);
  F16* Hb  = (F16*)alloc((size_t)ROWS * FF * 2);
  int* rowtok = (int*)alloc((size_t)SBASE * 4);
  int* meta = (int*)alloc(2048);
  int* te0 = (int*)alloc((size_t)NTOK * 4);
  int* te1 = (int*)alloc((size_t)NTOK * 4);
  float* tw0 = (float*)alloc((size_t)NTOK * 4);
  float* tw1 = (float*)alloc((size_t)NTOK * 4);
  int* sl0 = (int*)alloc((size_t)NTOK * 4);
  int* sl1 = (int*)alloc((size_t)NTOK * 4);
  if (o > ws_size) return;
  F16* Yb = WGU;   // overlay: WGU dead after gemm1; Y (54.5MB) < WGU (75.5MB)

  hipMemsetAsync(meta, 0, 1024, stream);
  k_prep<<<NBWGU + NBWD + NBRT, 256, 0, stream>>>(
      x, rw, wgate, sg, wup, su, wdown, sd, WGU, WD, xh,
      meta, te0, te1, tw0, tw1);
  k_scan<<<1, 256, 0, stream>>>(meta, rowtok);
  k_scatter<<<NTOK / 256, 256, 0, stream>>>(te0, te1, meta, rowtok, sl0, sl1);
  k_gemm<true><<<dim3(MAXT, 2 * FF / 256), 512, 0, stream>>>(xh, WGU, Hb, meta, rowtok);
  k_gemm<false><<<dim3(MAXT, C / 256), 512, 0, stream>>>(Hb, WD, Yb, meta, rowtok);
  k_combine<<<NTOK * (C / 8) / 256, 256, 0, stream>>>(Yb, sl0, sl1, tw0, tw1, out);
}